// Round 12
// baseline (1485.112 us; speedup 1.0000x reference)
//
#include <hip/hip_runtime.h>
#include <hip/hip_bf16.h>

#define NN 100000
#define EE 1600000
#define DD 128
#define EPSc 0.1f
#define NBK 256        // dst-range buckets
#define BKDIV 391      // dsts per bucket (391*256 >= NN)
#define BKCAP 7168     // max edges per bucket (avg 6250, >10 sigma pad)
#define PL ((size_t)NN * 64)   // fp8 plane stride: dims 0..63 / 64..127

typedef unsigned short bfu;
typedef __attribute__((ext_vector_type(8))) short short8;   // 8 bf16 = 4 VGPRs
typedef __attribute__((ext_vector_type(4))) float f32x4;
typedef __attribute__((ext_vector_type(2))) float f32x2;

__device__ __forceinline__ float bf2f(bfu s) {
    union { unsigned u; float f; } c; c.u = ((unsigned)s) << 16; return c.f;
}
__device__ __forceinline__ bfu f2bf(float f) {
    union { float f; unsigned u; } c; c.f = f;
    unsigned u = c.u + 0x7fffu + ((c.u >> 16) & 1u);   // RNE
    return (bfu)(u >> 16);
}
__device__ __forceinline__ unsigned pk8(float a, float b, float c, float d) {
    int r = 0;
    r = __builtin_amdgcn_cvt_pk_fp8_f32(a, b, r, false);
    r = __builtin_amdgcn_cvt_pk_fp8_f32(c, d, r, true);
    return (unsigned)r;
}
__device__ __forceinline__ unsigned char enc8(float a) {
    return (unsigned char)(__builtin_amdgcn_cvt_pk_fp8_f32(a, a, 0, false) & 0xFF);
}
__device__ __forceinline__ short8 e8bf(uint2 u) {
    f32x2 p0 = __builtin_amdgcn_cvt_pk_f32_fp8((int)u.x, false);
    f32x2 p1 = __builtin_amdgcn_cvt_pk_f32_fp8((int)u.x, true);
    f32x2 p2 = __builtin_amdgcn_cvt_pk_f32_fp8((int)u.y, false);
    f32x2 p3 = __builtin_amdgcn_cvt_pk_f32_fp8((int)u.y, true);
    short8 s;
    s[0] = (short)f2bf(p0[0]); s[1] = (short)f2bf(p0[1]);
    s[2] = (short)f2bf(p1[0]); s[3] = (short)f2bf(p1[1]);
    s[4] = (short)f2bf(p2[0]); s[5] = (short)f2bf(p2[1]);
    s[6] = (short)f2bf(p3[0]); s[7] = (short)f2bf(p3[1]);
    return s;
}
// fast tanh: (e^{2x}-1)/(e^{2x}+1), clamped so exp can't overflow
__device__ __forceinline__ float ftanh(float x) {
    float xc = fminf(fmaxf(x, -9.0f), 9.0f);
    float e = __expf(2.0f * xc);
    return (e - 1.0f) * __builtin_amdgcn_rcpf(e + 1.0f);
}

// ---------------- CSR build ----------------

__global__ __launch_bounds__(256) void count_deg_kernel(const int* __restrict__ dst,
                                                        int* __restrict__ ideg, int e_cnt) {
    int e = blockIdx.x * 256 + threadIdx.x;
    if (e < e_cnt) atomicAdd(&ideg[dst[e]], 1);
}

__global__ __launch_bounds__(256) void dinv_kernel(const int* __restrict__ ideg,
                                                   float* __restrict__ dinv, int n) {
    int i = blockIdx.x * 256 + threadIdx.x;
    if (i < n) {
        int d = ideg[i];
        dinv[i] = (d > 0) ? rsqrtf((float)d) : 0.0f;
    }
}

__global__ __launch_bounds__(256) void partial_sum_kernel(const int* __restrict__ ideg,
                                                          int* __restrict__ partials, int n) {
    __shared__ int sm[256];
    int i = blockIdx.x * 256 + threadIdx.x;
    sm[threadIdx.x] = (i < n) ? ideg[i] : 0;
    __syncthreads();
    for (int off = 128; off > 0; off >>= 1) {
        if ((int)threadIdx.x < off) sm[threadIdx.x] += sm[threadIdx.x + off];
        __syncthreads();
    }
    if (threadIdx.x == 0) partials[blockIdx.x] = sm[0];
}

__global__ __launch_bounds__(512) void scan_partials_kernel(int* __restrict__ partials,
                                                            int* __restrict__ row_ptr,
                                                            int nb, int n) {
    __shared__ int sm[512];
    int v = ((int)threadIdx.x < nb) ? partials[threadIdx.x] : 0;
    sm[threadIdx.x] = v;
    __syncthreads();
    for (int off = 1; off < 512; off <<= 1) {
        int t = (threadIdx.x >= (unsigned)off) ? sm[threadIdx.x - off] : 0;
        __syncthreads();
        sm[threadIdx.x] += t;
        __syncthreads();
    }
    if ((int)threadIdx.x < nb) partials[threadIdx.x] = sm[threadIdx.x] - v;
    if (threadIdx.x == 511) row_ptr[n] = sm[511];
}

__global__ __launch_bounds__(256) void scan_block_kernel(const int* __restrict__ ideg,
                                                         const int* __restrict__ partials,
                                                         int* __restrict__ row_ptr, int n) {
    __shared__ int sm[256];
    int i = blockIdx.x * 256 + threadIdx.x;
    int v = (i < n) ? ideg[i] : 0;
    sm[threadIdx.x] = v;
    __syncthreads();
    for (int off = 1; off < 256; off <<= 1) {
        int t = (threadIdx.x >= (unsigned)off) ? sm[threadIdx.x - off] : 0;
        __syncthreads();
        sm[threadIdx.x] += t;
        __syncthreads();
    }
    if (i < n) row_ptr[i] = partials[blockIdx.x] + sm[threadIdx.x] - v;
}

// pass 1: bin edges into 256 dst-range buckets (LDS histogram -> one global
// cursor update per (block,bucket); segment writes coalesce).
__global__ __launch_bounds__(256) void bin_kernel(const int* __restrict__ src,
                                                  const int* __restrict__ dst,
                                                  int* __restrict__ bcur,
                                                  uint2* __restrict__ store, int e_cnt) {
    __shared__ int lcnt[NBK];
    __shared__ int lbase[NBK];
    int e0 = blockIdx.x * 4096;
    lcnt[threadIdx.x] = 0;
    __syncthreads();
    for (int k = 0; k < 16; ++k) {
        int e = e0 + k * 256 + (int)threadIdx.x;
        if (e < e_cnt) atomicAdd(&lcnt[(unsigned)dst[e] / BKDIV], 1);
    }
    __syncthreads();
    int c = lcnt[threadIdx.x];
    lbase[threadIdx.x] = (c > 0) ? atomicAdd(&bcur[threadIdx.x], c) : 0;
    __syncthreads();
    lcnt[threadIdx.x] = 0;
    __syncthreads();
    for (int k = 0; k < 16; ++k) {
        int e = e0 + k * 256 + (int)threadIdx.x;
        if (e < e_cnt) {
            int d = dst[e];
            unsigned b = (unsigned)d / BKDIV;
            int p = atomicAdd(&lcnt[b], 1);
            int idx = lbase[b] + p;
            if (idx < BKCAP)
                store[(size_t)b * BKCAP + idx] = make_uint2((unsigned)src[e], (unsigned)d);
        }
    }
}

// pass 2: one block per bucket; place into L2-local cvp window via LDS cursors.
// packed edge: top 15 bits = f32 val bits[31:17], low 17 = col.
__global__ __launch_bounds__(256) void place_kernel(const uint2* __restrict__ store,
                                                    const int* __restrict__ bcur,
                                                    const int* __restrict__ row_ptr,
                                                    const float* __restrict__ dinv,
                                                    unsigned* __restrict__ cvp) {
    __shared__ int cur[BKDIV];
    int g = blockIdx.x;
    int d0 = g * BKDIV;
    for (int i = threadIdx.x; i < BKDIV; i += 256) {
        int d = d0 + i;
        cur[i] = (d < NN) ? row_ptr[d] : 0;
    }
    __syncthreads();
    int cnt = bcur[g];
    if (cnt > BKCAP) cnt = BKCAP;
    for (int i = threadIdx.x; i < cnt; i += 256) {
        uint2 w = store[(size_t)g * BKCAP + i];
        int s = (int)w.x, d = (int)w.y;
        int pos = atomicAdd(&cur[d - d0], 1);
        unsigned vb = __float_as_uint(dinv[s] * dinv[d]);
        unsigned r = vb + 0xFFFFu + ((vb >> 17) & 1u);   // RNE to 15-bit float
        cvp[pos] = (r & 0xFFFE0000u) | (unsigned)s;
    }
}

// ------------- weight -> bf16 MFMA-fragment-order transform (5 matrices) -------------

__global__ __launch_bounds__(256) void wfrag_kernel(const float* __restrict__ conv_ws,
                                                    const float* __restrict__ ro_w,
                                                    const float* __restrict__ emb_w,
                                                    bfu* __restrict__ Wf) {
    int m = blockIdx.x;   // 0..4
    const float* W = (m < 3) ? conv_ws + m * 16384 : (m == 3 ? ro_w : emb_w);
    bfu* T = Wf + m * 16384;
    for (int j = 0; j < 64; ++j) {
        int i = threadIdx.x + j * 256;       // i = k*128 + n
        int k = i >> 7, n = i & 127;
        int nt = n >> 4, ks = k >> 5, kg = (k >> 3) & 3, jj = k & 7;
        int l = kg * 16 + (n & 15);
        int flat = ((nt * 4 + ks) * 64 + l) * 8 + jj;
        T[flat] = f2bf(W[i]);
    }
}

// ---------------- propagation on a 64-dim PLANE (fp8 in/out, f32 accum) ----------------
// 64-B rows = one cache line per edge. 8 lanes x 8B per row, 8 edge groups,
// 4 slots in flight (32 B/lane, same ILP as the proven full-row shape).
// Plane-split keeps the gather-hot set at 6.4 MB -> better per-XCD L2 residency.

__device__ __forceinline__ void acc8f8(uint2 u, float v, float* acc) {
    f32x2 p0 = __builtin_amdgcn_cvt_pk_f32_fp8((int)u.x, false);
    f32x2 p1 = __builtin_amdgcn_cvt_pk_f32_fp8((int)u.x, true);
    f32x2 p2 = __builtin_amdgcn_cvt_pk_f32_fp8((int)u.y, false);
    f32x2 p3 = __builtin_amdgcn_cvt_pk_f32_fp8((int)u.y, true);
    acc[0] = fmaf(v, p0[0], acc[0]); acc[1] = fmaf(v, p0[1], acc[1]);
    acc[2] = fmaf(v, p1[0], acc[2]); acc[3] = fmaf(v, p1[1], acc[3]);
    acc[4] = fmaf(v, p2[0], acc[4]); acc[5] = fmaf(v, p2[1], acc[5]);
    acc[6] = fmaf(v, p3[0], acc[6]); acc[7] = fmaf(v, p3[1], acc[7]);
}

__global__ __launch_bounds__(256) void prop_kernel(const unsigned char* __restrict__ xin8,
                                                   unsigned char* __restrict__ out8,
                                                   const int* __restrict__ row_ptr,
                                                   const unsigned* __restrict__ cvp, int n) {
    int wid = (blockIdx.x * 256 + threadIdx.x) >> 6;  // one wave per node
    int lane = threadIdx.x & 63;
    if (wid >= n) return;
    int s = row_ptr[wid];
    int deg = row_ptr[wid + 1] - s;
    int g = lane >> 3;        // edge slot group 0..7
    int li = lane & 7;        // 8 lanes cover the 64-B plane row (8 B each)
    float acc[8] = {0.f, 0.f, 0.f, 0.f, 0.f, 0.f, 0.f, 0.f};
    for (int base = 0; base < deg; base += 64) {
        int cnt = deg - base; if (cnt > 64) cnt = 64;
        unsigned el = (lane < cnt) ? cvp[s + base + lane] : 0u;   // coalesced
        for (int q = 0; q < cnt; q += 32) {
            uint2 x[4]; float v[4];
            #pragma unroll
            for (int j = 0; j < 4; ++j) {
                int idx = q + j * 8 + g;
                unsigned c = __shfl(el, idx);
                bool valid = idx < cnt;
                v[j] = valid ? __uint_as_float(c & 0xFFFE0000u) : 0.f;
                x[j] = valid ? *(const uint2*)(xin8 + (size_t)(c & 0x1FFFFu) * 64 + li * 8)
                             : make_uint2(0u, 0u);
            }
            #pragma unroll
            for (int j = 0; j < 4; ++j) acc8f8(x[j], v[j], acc);
        }
    }
    #pragma unroll
    for (int k = 0; k < 8; ++k) {
        acc[k] += __shfl_xor(acc[k], 8);
        acc[k] += __shfl_xor(acc[k], 16);
        acc[k] += __shfl_xor(acc[k], 32);
    }
    if (g == 0) {
        uint2 q;
        q.x = pk8(acc[0], acc[1], acc[2], acc[3]);
        q.y = pk8(acc[4], acc[5], acc[6], acc[7]);
        *(uint2*)(out8 + (size_t)wid * 64 + li * 8) = q;
    }
}

// ---------------- MFMA matmul: acc = sum_m A_m @ W_m, fused epilogue ----------------
// A streams are 2-plane fp8 ([plane][N][64]); base16 is full-width bf16.
// TANH: v = bf2f(base16) + scale*ftanh(acc+bias); outf?=v, out16?=v(bf16), out8=fp8(v)
// RO (requires TANH): additionally y = v_tile @ Wro + rob via per-wave LDS transpose.

template <int NMAT, bool TANH, bool RO>
__global__ __launch_bounds__(256) void mfma_mm_kernel(const unsigned char* __restrict__ A0,
                                                      const unsigned char* __restrict__ A1,
                                                      const unsigned char* __restrict__ A2,
                                                      const bfu* __restrict__ Wf,
                                                      const float* __restrict__ bias,
                                                      const bfu* __restrict__ base16,
                                                      float* __restrict__ outf,
                                                      bfu* __restrict__ out16,
                                                      unsigned char* __restrict__ out8,
                                                      const bfu* __restrict__ Wro,
                                                      const float* __restrict__ rob,
                                                      float* __restrict__ yout,
                                                      float scale) {
    int tid = threadIdx.x;
    int wave = tid >> 6, lane = tid & 63;
    int r0 = blockIdx.x * 64 + wave * 16;
    int li = lane & 15, kg = lane >> 4;
    int rowA = r0 + li;
    bool rv = rowA < NN;
    size_t arow = (size_t)(rv ? rowA : 0) * 64;   // plane-row bytes

    const unsigned char* As[3] = {A0, A1, A2};
    short8 a[NMAT][4];
    #pragma unroll
    for (int m = 0; m < NMAT; ++m) {
        #pragma unroll
        for (int ks = 0; ks < 4; ++ks) {
            // dims [ks*32+kg*8 .. +8): plane = ks>>1, in-row offset = (ks&1)*32 + kg*8
            uint2 u = *(const uint2*)(As[m] + (size_t)(ks >> 1) * PL + arow + (ks & 1) * 32 + kg * 8);
            short8 t = e8bf(u);
            if (!rv) t = (short8)0;
            a[m][ks] = t;
        }
    }

    const short8* Bp = (const short8*)Wf;   // [NMAT][32][64] short8
    f32x4 acc[8];
    #pragma unroll
    for (int nt = 0; nt < 8; ++nt) acc[nt] = (f32x4)(0.f);
    #pragma unroll
    for (int nt = 0; nt < 8; ++nt) {
        #pragma unroll
        for (int m = 0; m < NMAT; ++m) {
            #pragma unroll
            for (int ks = 0; ks < 4; ++ks) {
                short8 b = Bp[m * 2048 + (nt * 4 + ks) * 64 + lane];
                acc[nt] = __builtin_amdgcn_mfma_f32_16x16x32_bf16(a[m][ks], b, acc[nt], 0, 0, 0);
            }
        }
    }

    __shared__ bfu lds_a[RO ? 4 : 1][RO ? 2048 : 1];
    bfu* myt = &lds_a[RO ? wave : 0][0];

    #pragma unroll
    for (int nt = 0; nt < 8; ++nt) {
        int cc = nt * 16 + li;
        float bv = bias[cc];
        #pragma unroll
        for (int rg = 0; rg < 4; ++rg) {
            int rr = r0 + kg * 4 + rg;
            bool v = rr < NN;
            size_t off = (size_t)(v ? rr : 0) * DD + cc;
            float o = acc[nt][rg];
            if (TANH) {
                float ov = v ? (bf2f(base16[off]) + scale * ftanh(o + bv)) : 0.f;
                if (v) {
                    if (outf) outf[off] = ov;
                    if (out16) out16[off] = f2bf(ov);
                    out8[(size_t)(nt >> 2) * PL + (size_t)rr * 64 + ((nt & 3) * 16 + li)] = enc8(ov);
                }
                if (RO) {
                    int ks = nt >> 1;
                    int kgk = ((nt & 1) << 1) | (li >> 3);
                    int j = li & 7;
                    int row = kg * 4 + rg;
                    myt[(ks * 64 + kgk * 16 + row) * 8 + j] = f2bf(ov);
                }
            } else {
                if (v) outf[off] = o + bv;
            }
        }
    }

    if (RO) {
        short8 ar[4];
        #pragma unroll
        for (int ks = 0; ks < 4; ++ks)
            ar[ks] = *(const short8*)&myt[(ks * 64 + lane) * 8];
        const short8* Bro = (const short8*)Wro;
        #pragma unroll
        for (int nt = 0; nt < 8; ++nt) {
            f32x4 ay = (f32x4)(0.f);
            #pragma unroll
            for (int ks = 0; ks < 4; ++ks)
                ay = __builtin_amdgcn_mfma_f32_16x16x32_bf16(ar[ks], Bro[(nt * 4 + ks) * 64 + lane], ay, 0, 0, 0);
            int cc = nt * 16 + li;
            float bv = rob[cc];
            #pragma unroll
            for (int rg = 0; rg < 4; ++rg) {
                int rr = r0 + kg * 4 + rg;
                if (rr < NN) yout[(size_t)rr * DD + cc] = ay[rg] + bv;
            }
        }
    }
}

// ---------------- embedding via MFMA: h = x@emb_w + emb_b -> bf16 + fp8 planes ----------------

__global__ __launch_bounds__(256) void emb_mfma_kernel(const float* __restrict__ x,
                                                       const bfu* __restrict__ Wfe,
                                                       const float* __restrict__ bias,
                                                       bfu* __restrict__ out16,
                                                       unsigned char* __restrict__ out8) {
    int tid = threadIdx.x;
    int wave = tid >> 6, lane = tid & 63;
    int r0 = blockIdx.x * 64 + wave * 16;
    int li = lane & 15, kg = lane >> 4;
    int rowA = r0 + li;
    bool rv = rowA < NN;
    size_t arow = (size_t)(rv ? rowA : 0) * DD;

    short8 a[4];
    #pragma unroll
    for (int ks = 0; ks < 4; ++ks) {
        const float* px = x + arow + ks * 32 + kg * 8;
        float4 lo = *(const float4*)px;
        float4 hi = *(const float4*)(px + 4);
        short8 t;
        t[0] = (short)f2bf(lo.x); t[1] = (short)f2bf(lo.y);
        t[2] = (short)f2bf(lo.z); t[3] = (short)f2bf(lo.w);
        t[4] = (short)f2bf(hi.x); t[5] = (short)f2bf(hi.y);
        t[6] = (short)f2bf(hi.z); t[7] = (short)f2bf(hi.w);
        if (!rv) t = (short8)0;
        a[ks] = t;
    }

    const short8* Bp = (const short8*)Wfe;
    #pragma unroll
    for (int nt = 0; nt < 8; ++nt) {
        f32x4 acc = (f32x4)(0.f);
        #pragma unroll
        for (int ks = 0; ks < 4; ++ks)
            acc = __builtin_amdgcn_mfma_f32_16x16x32_bf16(a[ks], Bp[(nt * 4 + ks) * 64 + lane], acc, 0, 0, 0);
        int cc = nt * 16 + li;
        float bv = bias[cc];
        #pragma unroll
        for (int rg = 0; rg < 4; ++rg) {
            int rr = r0 + kg * 4 + rg;
            if (rr < NN) {
                size_t off = (size_t)rr * DD + cc;
                float o = acc[rg] + bv;
                out16[off] = f2bf(o);
                out8[(size_t)(nt >> 2) * PL + (size_t)rr * 64 + ((nt & 3) * 16 + li)] = enc8(o);
            }
        }
    }
}

// ---------------- launch ----------------

extern "C" void kernel_launch(void* const* d_in, const int* in_sizes, int n_in,
                              void* d_out, int out_size, void* d_ws, size_t ws_size,
                              hipStream_t stream) {
    const float* x      = (const float*)d_in[0];
    const int*   eidx   = (const int*)d_in[1];
    const float* emb_w  = (const float*)d_in[3];
    const float* emb_b  = (const float*)d_in[4];
    const float* conv_ws = (const float*)d_in[5];
    const float* conv_b = (const float*)d_in[6];
    const float* ro_w   = (const float*)d_in[7];
    const float* ro_b   = (const float*)d_in[8];

    const int* src = eidx;
    const int* dst = eidx + EE;

    float* y  = (float*)d_out;                   // [N,128] final output
    float* hm = y + (size_t)NN * DD;             // [N,128] h_middle f32 output

    char* p = (char*)d_ws;
    const size_t FB2 = (size_t)NN * DD * sizeof(bfu);   // 25.6 MB
    bfu* h16     = (bfu*)p;                 p += FB2;   // bf16 master state (full-width)
    unsigned char* h8  = (unsigned char*)p; p += 2 * PL;   // fp8, 2 planes
    unsigned char* hm8 = (unsigned char*)p; p += 2 * PL;
    unsigned char* bufA8 = (unsigned char*)p; p += 2 * PL;
    unsigned char* bufB8 = (unsigned char*)p; p += 2 * PL;
    float* dinv  = (float*)p;               p += (size_t)NN * 4;
    int* ideg    = (int*)p;                 p += (size_t)NN * 4;
    int* row_ptr = (int*)p;                 p += (size_t)(NN + 1) * 4;
    int* partials = (int*)p;                p += (size_t)512 * 4;
    int* bcur    = (int*)p;                 p += (size_t)NBK * 4;
    uint2* store = (uint2*)p;               p += (size_t)NBK * BKCAP * 8;  // 14.7 MB
    bfu* Wf      = (bfu*)p;                 p += (size_t)5 * 16384 * sizeof(bfu);
    unsigned* cvp = (unsigned*)p;           p += (size_t)EE * 4;

    const int NB = (NN + 255) / 256;   // 391
    const int EB = (EE + 4095) / 4096; // 391

    hipMemsetAsync(ideg, 0, (size_t)NN * 4, stream);
    hipMemsetAsync(bcur, 0, (size_t)NBK * 4, stream);
    count_deg_kernel<<<EE / 256, 256, 0, stream>>>(dst, ideg, EE);
    dinv_kernel<<<NB, 256, 0, stream>>>(ideg, dinv, NN);
    partial_sum_kernel<<<NB, 256, 0, stream>>>(ideg, partials, NN);
    scan_partials_kernel<<<1, 512, 0, stream>>>(partials, row_ptr, NB, NN);
    scan_block_kernel<<<NB, 256, 0, stream>>>(ideg, partials, row_ptr, NN);
    bin_kernel<<<EB, 256, 0, stream>>>(src, dst, bcur, store, EE);
    place_kernel<<<NBK, 256, 0, stream>>>(store, bcur, row_ptr, dinv, cvp);
    wfrag_kernel<<<5, 256, 0, stream>>>(conv_ws, ro_w, emb_w, Wf);

    const int MM_GRID   = (NN + 63) / 64;     // 1563
    const int PROP_GRID = NN * 64 / 256;      // 25000

    // h = x @ emb_w + emb_b  (bf16 master + fp8 planes)
    emb_mfma_kernel<<<MM_GRID, 256, 0, stream>>>(x, Wf + 4 * 16384, emb_b, h16, h8);

    for (int t = 0; t < 4; ++t) {
        // hm = h + 0.05*tanh(h@W0 + (Ph)@W1 + (P2h)@W2 + b): per-plane K-chain
        for (int pl = 0; pl < 2; ++pl) {
            prop_kernel<<<PROP_GRID, 256, 0, stream>>>(h8 + pl * PL, bufA8 + pl * PL, row_ptr, cvp, NN);
            prop_kernel<<<PROP_GRID, 256, 0, stream>>>(bufA8 + pl * PL, bufB8 + pl * PL, row_ptr, cvp, NN);
        }
        if (t < 3) {
            mfma_mm_kernel<3, true, false><<<MM_GRID, 256, 0, stream>>>(
                h8, bufA8, bufB8, Wf, conv_b, h16,
                nullptr, nullptr, hm8, nullptr, nullptr, nullptr, 0.5f * EPSc);

            // h = h + 0.1*tanh(hm@W0 + (Phm)@W1 + (P2hm)@W2 + b)
            for (int pl = 0; pl < 2; ++pl) {
                prop_kernel<<<PROP_GRID, 256, 0, stream>>>(hm8 + pl * PL, bufA8 + pl * PL, row_ptr, cvp, NN);
                prop_kernel<<<PROP_GRID, 256, 0, stream>>>(bufA8 + pl * PL, bufB8 + pl * PL, row_ptr, cvp, NN);
            }
            mfma_mm_kernel<3, true, false><<<MM_GRID, 256, 0, stream>>>(
                hm8, bufA8, bufB8, Wf, conv_b, h16,
                nullptr, h16, h8, nullptr, nullptr, nullptr, EPSc);
        } else {
            // final midpoint: write hm (f32 output) + hm8, fuse y = hm @ ro_w + ro_b.
            // The trailing h-update of the reference is dead code (h never read again).
            mfma_mm_kernel<3, true, true><<<MM_GRID, 256, 0, stream>>>(
                h8, bufA8, bufB8, Wf, conv_b, h16,
                hm, nullptr, hm8, Wf + 3 * 16384, ro_b, y, 0.5f * EPSc);
        }
    }
}

// Round 13
// 1089.018 us; speedup vs baseline: 1.3637x; 1.3637x over previous
//
#include <hip/hip_runtime.h>
#include <hip/hip_bf16.h>

#define NN 100000
#define EE 1600000
#define DD 128
#define EPSc 0.1f
#define NBK 256        // dst-range buckets
#define BKDIV 391      // dsts per bucket (391*256 >= NN)
#define BKCAP 7168     // max edges per bucket (avg 6250, >10 sigma pad)

typedef unsigned short bfu;
typedef __attribute__((ext_vector_type(8))) short short8;   // 8 bf16 = 4 VGPRs
typedef __attribute__((ext_vector_type(4))) float f32x4;
typedef __attribute__((ext_vector_type(2))) float f32x2;

__device__ __forceinline__ float bf2f(bfu s) {
    union { unsigned u; float f; } c; c.u = ((unsigned)s) << 16; return c.f;
}
__device__ __forceinline__ bfu f2bf(float f) {
    union { float f; unsigned u; } c; c.f = f;
    unsigned u = c.u + 0x7fffu + ((c.u >> 16) & 1u);   // RNE
    return (bfu)(u >> 16);
}
__device__ __forceinline__ unsigned pk8(float a, float b, float c, float d) {
    int r = 0;
    r = __builtin_amdgcn_cvt_pk_fp8_f32(a, b, r, false);
    r = __builtin_amdgcn_cvt_pk_fp8_f32(c, d, r, true);
    return (unsigned)r;
}
__device__ __forceinline__ unsigned char enc8(float a) {
    return (unsigned char)(__builtin_amdgcn_cvt_pk_fp8_f32(a, a, 0, false) & 0xFF);
}
__device__ __forceinline__ short8 e8bf(uint2 u) {
    f32x2 p0 = __builtin_amdgcn_cvt_pk_f32_fp8((int)u.x, false);
    f32x2 p1 = __builtin_amdgcn_cvt_pk_f32_fp8((int)u.x, true);
    f32x2 p2 = __builtin_amdgcn_cvt_pk_f32_fp8((int)u.y, false);
    f32x2 p3 = __builtin_amdgcn_cvt_pk_f32_fp8((int)u.y, true);
    short8 s;
    s[0] = (short)f2bf(p0[0]); s[1] = (short)f2bf(p0[1]);
    s[2] = (short)f2bf(p1[0]); s[3] = (short)f2bf(p1[1]);
    s[4] = (short)f2bf(p2[0]); s[5] = (short)f2bf(p2[1]);
    s[6] = (short)f2bf(p3[0]); s[7] = (short)f2bf(p3[1]);
    return s;
}
// fast tanh: (e^{2x}-1)/(e^{2x}+1), clamped so exp can't overflow
__device__ __forceinline__ float ftanh(float x) {
    float xc = fminf(fmaxf(x, -9.0f), 9.0f);
    float e = __expf(2.0f * xc);
    return (e - 1.0f) * __builtin_amdgcn_rcpf(e + 1.0f);
}

// ---------------- CSR build ----------------

__global__ __launch_bounds__(256) void count_deg_kernel(const int* __restrict__ dst,
                                                        int* __restrict__ ideg, int e_cnt) {
    int e = blockIdx.x * 256 + threadIdx.x;
    if (e < e_cnt) atomicAdd(&ideg[dst[e]], 1);
}

__global__ __launch_bounds__(256) void dinv_kernel(const int* __restrict__ ideg,
                                                   float* __restrict__ dinv, int n) {
    int i = blockIdx.x * 256 + threadIdx.x;
    if (i < n) {
        int d = ideg[i];
        dinv[i] = (d > 0) ? rsqrtf((float)d) : 0.0f;
    }
}

__global__ __launch_bounds__(256) void partial_sum_kernel(const int* __restrict__ ideg,
                                                          int* __restrict__ partials, int n) {
    __shared__ int sm[256];
    int i = blockIdx.x * 256 + threadIdx.x;
    sm[threadIdx.x] = (i < n) ? ideg[i] : 0;
    __syncthreads();
    for (int off = 128; off > 0; off >>= 1) {
        if ((int)threadIdx.x < off) sm[threadIdx.x] += sm[threadIdx.x + off];
        __syncthreads();
    }
    if (threadIdx.x == 0) partials[blockIdx.x] = sm[0];
}

__global__ __launch_bounds__(512) void scan_partials_kernel(int* __restrict__ partials,
                                                            int* __restrict__ row_ptr,
                                                            int nb, int n) {
    __shared__ int sm[512];
    int v = ((int)threadIdx.x < nb) ? partials[threadIdx.x] : 0;
    sm[threadIdx.x] = v;
    __syncthreads();
    for (int off = 1; off < 512; off <<= 1) {
        int t = (threadIdx.x >= (unsigned)off) ? sm[threadIdx.x - off] : 0;
        __syncthreads();
        sm[threadIdx.x] += t;
        __syncthreads();
    }
    if ((int)threadIdx.x < nb) partials[threadIdx.x] = sm[threadIdx.x] - v;
    if (threadIdx.x == 511) row_ptr[n] = sm[511];
}

__global__ __launch_bounds__(256) void scan_block_kernel(const int* __restrict__ ideg,
                                                         const int* __restrict__ partials,
                                                         int* __restrict__ row_ptr, int n) {
    __shared__ int sm[256];
    int i = blockIdx.x * 256 + threadIdx.x;
    int v = (i < n) ? ideg[i] : 0;
    sm[threadIdx.x] = v;
    __syncthreads();
    for (int off = 1; off < 256; off <<= 1) {
        int t = (threadIdx.x >= (unsigned)off) ? sm[threadIdx.x - off] : 0;
        __syncthreads();
        sm[threadIdx.x] += t;
        __syncthreads();
    }
    if (i < n) row_ptr[i] = partials[blockIdx.x] + sm[threadIdx.x] - v;
}

// pass 1: bin edges into 256 dst-range buckets. Block-local LDS histogram ->
// ONE global cursor update per (block,bucket) -> no same-address atomic storm;
// segment writes are 128B-run coalesced.
__global__ __launch_bounds__(256) void bin_kernel(const int* __restrict__ src,
                                                  const int* __restrict__ dst,
                                                  int* __restrict__ bcur,
                                                  uint2* __restrict__ store, int e_cnt) {
    __shared__ int lcnt[NBK];
    __shared__ int lbase[NBK];
    int e0 = blockIdx.x * 4096;
    lcnt[threadIdx.x] = 0;
    __syncthreads();
    for (int k = 0; k < 16; ++k) {
        int e = e0 + k * 256 + (int)threadIdx.x;
        if (e < e_cnt) atomicAdd(&lcnt[(unsigned)dst[e] / BKDIV], 1);
    }
    __syncthreads();
    int c = lcnt[threadIdx.x];
    lbase[threadIdx.x] = (c > 0) ? atomicAdd(&bcur[threadIdx.x], c) : 0;
    __syncthreads();
    lcnt[threadIdx.x] = 0;
    __syncthreads();
    for (int k = 0; k < 16; ++k) {
        int e = e0 + k * 256 + (int)threadIdx.x;
        if (e < e_cnt) {
            int d = dst[e];
            unsigned b = (unsigned)d / BKDIV;
            int p = atomicAdd(&lcnt[b], 1);
            int idx = lbase[b] + p;
            if (idx < BKCAP)
                store[(size_t)b * BKCAP + idx] = make_uint2((unsigned)src[e], (unsigned)d);
        }
    }
}

// pass 2: one block per bucket; scatter into an L2-local 25KB cvp window via
// LDS per-dst cursors. packed edge: top 15 bits = f32 val bits[31:17], low 17 = col.
__global__ __launch_bounds__(256) void place_kernel(const uint2* __restrict__ store,
                                                    const int* __restrict__ bcur,
                                                    const int* __restrict__ row_ptr,
                                                    const float* __restrict__ dinv,
                                                    unsigned* __restrict__ cvp) {
    __shared__ int cur[BKDIV];
    int g = blockIdx.x;
    int d0 = g * BKDIV;
    for (int i = threadIdx.x; i < BKDIV; i += 256) {
        int d = d0 + i;
        cur[i] = (d < NN) ? row_ptr[d] : 0;
    }
    __syncthreads();
    int cnt = bcur[g];
    if (cnt > BKCAP) cnt = BKCAP;
    for (int i = threadIdx.x; i < cnt; i += 256) {
        uint2 w = store[(size_t)g * BKCAP + i];
        int s = (int)w.x, d = (int)w.y;
        int pos = atomicAdd(&cur[d - d0], 1);
        unsigned vb = __float_as_uint(dinv[s] * dinv[d]);
        unsigned r = vb + 0xFFFFu + ((vb >> 17) & 1u);   // RNE to 15-bit float
        cvp[pos] = (r & 0xFFFE0000u) | (unsigned)s;
    }
}

// ------------- weight -> bf16 MFMA-fragment-order transform (5 matrices) -------------

__global__ __launch_bounds__(256) void wfrag_kernel(const float* __restrict__ conv_ws,
                                                    const float* __restrict__ ro_w,
                                                    const float* __restrict__ emb_w,
                                                    bfu* __restrict__ Wf) {
    int m = blockIdx.x;   // 0..4
    const float* W = (m < 3) ? conv_ws + m * 16384 : (m == 3 ? ro_w : emb_w);
    bfu* T = Wf + m * 16384;
    for (int j = 0; j < 64; ++j) {
        int i = threadIdx.x + j * 256;       // i = k*128 + n
        int k = i >> 7, n = i & 127;
        int nt = n >> 4, ks = k >> 5, kg = (k >> 3) & 3, jj = k & 7;
        int l = kg * 16 + (n & 15);
        int flat = ((nt * 4 + ks) * 64 + l) * 8 + jj;
        T[flat] = f2bf(W[i]);
    }
}

// ---------------- propagation (fp8 in / fp8 out, f32 accum) ----------------
// 16 lanes x 8B per 128B row (line-exact), 4 edge groups, 2-deep unroll:
// 8 row-gathers in flight per wave. Proven local optimum (r6/r8/r12 bracketing).

__device__ __forceinline__ void acc8f8(uint2 u, float v, float* acc) {
    f32x2 p0 = __builtin_amdgcn_cvt_pk_f32_fp8((int)u.x, false);
    f32x2 p1 = __builtin_amdgcn_cvt_pk_f32_fp8((int)u.x, true);
    f32x2 p2 = __builtin_amdgcn_cvt_pk_f32_fp8((int)u.y, false);
    f32x2 p3 = __builtin_amdgcn_cvt_pk_f32_fp8((int)u.y, true);
    acc[0] = fmaf(v, p0[0], acc[0]); acc[1] = fmaf(v, p0[1], acc[1]);
    acc[2] = fmaf(v, p1[0], acc[2]); acc[3] = fmaf(v, p1[1], acc[3]);
    acc[4] = fmaf(v, p2[0], acc[4]); acc[5] = fmaf(v, p2[1], acc[5]);
    acc[6] = fmaf(v, p3[0], acc[6]); acc[7] = fmaf(v, p3[1], acc[7]);
}

__global__ __launch_bounds__(256) void prop_kernel(const unsigned char* __restrict__ xin8,
                                                   unsigned char* __restrict__ out8,
                                                   const int* __restrict__ row_ptr,
                                                   const unsigned* __restrict__ cvp, int n) {
    int wid = (blockIdx.x * 256 + threadIdx.x) >> 6;  // one wave per node
    int lane = threadIdx.x & 63;
    if (wid >= n) return;
    int s = row_ptr[wid];
    int deg = row_ptr[wid + 1] - s;
    int g = lane >> 4;        // edge slot group 0..3
    int li = lane & 15;       // 16 lanes cover 128 dims (8 fp8 bytes each)
    float acc[8] = {0.f, 0.f, 0.f, 0.f, 0.f, 0.f, 0.f, 0.f};
    for (int base = 0; base < deg; base += 64) {
        int cnt = deg - base; if (cnt > 64) cnt = 64;
        unsigned el = (lane < cnt) ? cvp[s + base + lane] : 0u;   // coalesced
        for (int q = 0; q < cnt; q += 16) {
            uint2 x[4]; float v[4];
            #pragma unroll
            for (int j = 0; j < 4; ++j) {
                int idx = q + j * 4 + g;
                unsigned c = __shfl(el, idx);
                bool valid = idx < cnt;
                v[j] = valid ? __uint_as_float(c & 0xFFFE0000u) : 0.f;
                x[j] = valid ? *(const uint2*)(xin8 + (size_t)(c & 0x1FFFFu) * DD + li * 8)
                             : make_uint2(0u, 0u);
            }
            #pragma unroll
            for (int j = 0; j < 4; ++j) acc8f8(x[j], v[j], acc);
        }
    }
    #pragma unroll
    for (int k = 0; k < 8; ++k) {
        acc[k] += __shfl_xor(acc[k], 16);
        acc[k] += __shfl_xor(acc[k], 32);
    }
    if (g == 0) {
        uint2 q;
        q.x = pk8(acc[0], acc[1], acc[2], acc[3]);
        q.y = pk8(acc[4], acc[5], acc[6], acc[7]);
        *(uint2*)(out8 + (size_t)wid * DD + li * 8) = q;
    }
}

// ---------------- MFMA matmul: acc = sum_m A_m @ W_m, fused epilogue ----------------
// 16 rows/wave, 64 rows/block.
// TANH: v = bf2f(base16) + scale*ftanh(acc+bias); outf?=v, out16?=v(bf16), out8=fp8(v)
// RO (requires TANH): additionally y = v_tile @ Wro + rob via per-wave LDS transpose.

template <int NMAT, bool TANH, bool A8, bool RO>
__global__ __launch_bounds__(256) void mfma_mm_kernel(const void* __restrict__ A0,
                                                      const void* __restrict__ A1,
                                                      const void* __restrict__ A2,
                                                      const bfu* __restrict__ Wf,
                                                      const float* __restrict__ bias,
                                                      const bfu* __restrict__ base16,
                                                      float* __restrict__ outf,
                                                      bfu* __restrict__ out16,
                                                      unsigned char* __restrict__ out8,
                                                      const bfu* __restrict__ Wro,
                                                      const float* __restrict__ rob,
                                                      float* __restrict__ yout,
                                                      float scale) {
    int tid = threadIdx.x;
    int wave = tid >> 6, lane = tid & 63;
    int r0 = blockIdx.x * 64 + wave * 16;
    int li = lane & 15, kg = lane >> 4;
    int rowA = r0 + li;
    bool rv = rowA < NN;
    size_t arow = (size_t)(rv ? rowA : 0) * DD;   // elements

    const void* As[3] = {A0, A1, A2};
    short8 a[NMAT][4];
    #pragma unroll
    for (int m = 0; m < NMAT; ++m) {
        #pragma unroll
        for (int ks = 0; ks < 4; ++ks) {
            short8 t;
            if (A8) {
                uint2 u = *(const uint2*)((const unsigned char*)As[m] + arow + ks * 32 + kg * 8);
                t = e8bf(u);
            } else {
                t = *(const short8*)((const bfu*)As[m] + arow + ks * 32 + kg * 8);
            }
            if (!rv) t = (short8)0;
            a[m][ks] = t;
        }
    }

    const short8* Bp = (const short8*)Wf;   // [NMAT][32][64] short8
    f32x4 acc[8];
    #pragma unroll
    for (int nt = 0; nt < 8; ++nt) acc[nt] = (f32x4)(0.f);
    #pragma unroll
    for (int nt = 0; nt < 8; ++nt) {
        #pragma unroll
        for (int m = 0; m < NMAT; ++m) {
            #pragma unroll
            for (int ks = 0; ks < 4; ++ks) {
                short8 b = Bp[m * 2048 + (nt * 4 + ks) * 64 + lane];
                acc[nt] = __builtin_amdgcn_mfma_f32_16x16x32_bf16(a[m][ks], b, acc[nt], 0, 0, 0);
            }
        }
    }

    __shared__ bfu lds_a[RO ? 4 : 1][RO ? 2048 : 1];
    bfu* myt = &lds_a[RO ? wave : 0][0];

    #pragma unroll
    for (int nt = 0; nt < 8; ++nt) {
        int cc = nt * 16 + li;
        float bv = bias[cc];
        #pragma unroll
        for (int rg = 0; rg < 4; ++rg) {
            int rr = r0 + kg * 4 + rg;
            bool v = rr < NN;
            size_t off = (size_t)(v ? rr : 0) * DD + cc;
            float o = acc[nt][rg];
            if (TANH) {
                float ov = v ? (bf2f(base16[off]) + scale * ftanh(o + bv)) : 0.f;
                if (v) {
                    if (outf) outf[off] = ov;
                    if (out16) out16[off] = f2bf(ov);
                    out8[off] = enc8(ov);
                }
                if (RO) {
                    int ks = nt >> 1;
                    int kgk = ((nt & 1) << 1) | (li >> 3);
                    int j = li & 7;
                    int row = kg * 4 + rg;
                    myt[(ks * 64 + kgk * 16 + row) * 8 + j] = f2bf(ov);
                }
            } else {
                if (v) outf[off] = o + bv;
            }
        }
    }

    if (RO) {
        short8 ar[4];
        #pragma unroll
        for (int ks = 0; ks < 4; ++ks)
            ar[ks] = *(const short8*)&myt[(ks * 64 + lane) * 8];
        const short8* Bro = (const short8*)Wro;
        #pragma unroll
        for (int nt = 0; nt < 8; ++nt) {
            f32x4 ay = (f32x4)(0.f);
            #pragma unroll
            for (int ks = 0; ks < 4; ++ks)
                ay = __builtin_amdgcn_mfma_f32_16x16x32_bf16(ar[ks], Bro[(nt * 4 + ks) * 64 + lane], ay, 0, 0, 0);
            int cc = nt * 16 + li;
            float bv = rob[cc];
            #pragma unroll
            for (int rg = 0; rg < 4; ++rg) {
                int rr = r0 + kg * 4 + rg;
                if (rr < NN) yout[(size_t)rr * DD + cc] = ay[rg] + bv;
            }
        }
    }
}

// ---------------- embedding via MFMA: h = x@emb_w + emb_b -> bf16 + fp8 ----------------

__global__ __launch_bounds__(256) void emb_mfma_kernel(const float* __restrict__ x,
                                                       const bfu* __restrict__ Wfe,
                                                       const float* __restrict__ bias,
                                                       bfu* __restrict__ out16,
                                                       unsigned char* __restrict__ out8) {
    int tid = threadIdx.x;
    int wave = tid >> 6, lane = tid & 63;
    int r0 = blockIdx.x * 64 + wave * 16;
    int li = lane & 15, kg = lane >> 4;
    int rowA = r0 + li;
    bool rv = rowA < NN;
    size_t arow = (size_t)(rv ? rowA : 0) * DD;

    short8 a[4];
    #pragma unroll
    for (int ks = 0; ks < 4; ++ks) {
        const float* px = x + arow + ks * 32 + kg * 8;
        float4 lo = *(const float4*)px;
        float4 hi = *(const float4*)(px + 4);
        short8 t;
        t[0] = (short)f2bf(lo.x); t[1] = (short)f2bf(lo.y);
        t[2] = (short)f2bf(lo.z); t[3] = (short)f2bf(lo.w);
        t[4] = (short)f2bf(hi.x); t[5] = (short)f2bf(hi.y);
        t[6] = (short)f2bf(hi.z); t[7] = (short)f2bf(hi.w);
        if (!rv) t = (short8)0;
        a[ks] = t;
    }

    const short8* Bp = (const short8*)Wfe;
    #pragma unroll
    for (int nt = 0; nt < 8; ++nt) {
        f32x4 acc = (f32x4)(0.f);
        #pragma unroll
        for (int ks = 0; ks < 4; ++ks)
            acc = __builtin_amdgcn_mfma_f32_16x16x32_bf16(a[ks], Bp[(nt * 4 + ks) * 64 + lane], acc, 0, 0, 0);
        int cc = nt * 16 + li;
        float bv = bias[cc];
        #pragma unroll
        for (int rg = 0; rg < 4; ++rg) {
            int rr = r0 + kg * 4 + rg;
            if (rr < NN) {
                size_t off = (size_t)rr * DD + cc;
                float o = acc[rg] + bv;
                out16[off] = f2bf(o);
                out8[off] = enc8(o);
            }
        }
    }
}

// ---------------- launch ----------------

extern "C" void kernel_launch(void* const* d_in, const int* in_sizes, int n_in,
                              void* d_out, int out_size, void* d_ws, size_t ws_size,
                              hipStream_t stream) {
    const float* x      = (const float*)d_in[0];
    const int*   eidx   = (const int*)d_in[1];
    const float* emb_w  = (const float*)d_in[3];
    const float* emb_b  = (const float*)d_in[4];
    const float* conv_ws = (const float*)d_in[5];
    const float* conv_b = (const float*)d_in[6];
    const float* ro_w   = (const float*)d_in[7];
    const float* ro_b   = (const float*)d_in[8];

    const int* src = eidx;
    const int* dst = eidx + EE;

    float* y  = (float*)d_out;                   // [N,128] final output
    float* hm = y + (size_t)NN * DD;             // [N,128] h_middle f32 output

    char* p = (char*)d_ws;
    const size_t FB2 = (size_t)NN * DD * sizeof(bfu);   // 25.6 MB
    const size_t FB1 = (size_t)NN * DD;                 // 12.8 MB
    bfu* h16     = (bfu*)p;                 p += FB2;   // bf16 master state
    unsigned char* h8  = (unsigned char*)p; p += FB1;
    unsigned char* hm8 = (unsigned char*)p; p += FB1;
    unsigned char* bufA8 = (unsigned char*)p; p += FB1;
    unsigned char* bufB8 = (unsigned char*)p; p += FB1;
    float* dinv  = (float*)p;               p += (size_t)NN * 4;
    int* ideg    = (int*)p;                 p += (size_t)NN * 4;
    int* row_ptr = (int*)p;                 p += (size_t)(NN + 1) * 4;
    int* partials = (int*)p;                p += (size_t)512 * 4;
    int* bcur    = (int*)p;                 p += (size_t)NBK * 4;
    uint2* store = (uint2*)p;               p += (size_t)NBK * BKCAP * 8;  // 14.7 MB
    bfu* Wf      = (bfu*)p;                 p += (size_t)5 * 16384 * sizeof(bfu);
    unsigned* cvp = (unsigned*)p;           p += (size_t)EE * 4;

    const int NB = (NN + 255) / 256;   // 391
    const int EB = (EE + 4095) / 4096; // 391

    hipMemsetAsync(ideg, 0, (size_t)NN * 4, stream);
    hipMemsetAsync(bcur, 0, (size_t)NBK * 4, stream);
    count_deg_kernel<<<EE / 256, 256, 0, stream>>>(dst, ideg, EE);
    dinv_kernel<<<NB, 256, 0, stream>>>(ideg, dinv, NN);
    partial_sum_kernel<<<NB, 256, 0, stream>>>(ideg, partials, NN);
    scan_partials_kernel<<<1, 512, 0, stream>>>(partials, row_ptr, NB, NN);
    scan_block_kernel<<<NB, 256, 0, stream>>>(ideg, partials, row_ptr, NN);
    bin_kernel<<<EB, 256, 0, stream>>>(src, dst, bcur, store, EE);
    place_kernel<<<NBK, 256, 0, stream>>>(store, bcur, row_ptr, dinv, cvp);
    wfrag_kernel<<<5, 256, 0, stream>>>(conv_ws, ro_w, emb_w, Wf);

    const int MM_GRID   = (NN + 63) / 64;     // 1563
    const int PROP_GRID = NN * 64 / 256;      // 25000

    // h = x @ emb_w + emb_b  (bf16 master + fp8 shadow)
    emb_mfma_kernel<<<MM_GRID, 256, 0, stream>>>(x, Wf + 4 * 16384, emb_b, h16, h8);

    for (int t = 0; t < 4; ++t) {
        // hm = h + 0.05*tanh(h@W0 + (Ph)@W1 + (P2h)@W2 + b)
        prop_kernel<<<PROP_GRID, 256, 0, stream>>>(h8, bufA8, row_ptr, cvp, NN);
        prop_kernel<<<PROP_GRID, 256, 0, stream>>>(bufA8, bufB8, row_ptr, cvp, NN);
        if (t < 3) {
            mfma_mm_kernel<3, true, true, false><<<MM_GRID, 256, 0, stream>>>(
                h8, bufA8, bufB8, Wf, conv_b, h16,
                nullptr, nullptr, hm8, nullptr, nullptr, nullptr, 0.5f * EPSc);

            // h = h + 0.1*tanh(hm@W0 + (Phm)@W1 + (P2hm)@W2 + b)
            prop_kernel<<<PROP_GRID, 256, 0, stream>>>(hm8, bufA8, row_ptr, cvp, NN);
            prop_kernel<<<PROP_GRID, 256, 0, stream>>>(bufA8, bufB8, row_ptr, cvp, NN);
            mfma_mm_kernel<3, true, true, false><<<MM_GRID, 256, 0, stream>>>(
                hm8, bufA8, bufB8, Wf, conv_b, h16,
                nullptr, h16, h8, nullptr, nullptr, nullptr, EPSc);
        } else {
            // final midpoint: write hm (f32 output) + hm8, fuse y = hm @ ro_w + ro_b.
            // The trailing h-update of the reference is dead code (h never read again).
            mfma_mm_kernel<3, true, true, true><<<MM_GRID, 256, 0, stream>>>(
                h8, bufA8, bufB8, Wf, conv_b, h16,
                hm, nullptr, hm8, Wf + 3 * 16384, ro_b, y, 0.5f * EPSc);
        }
    }
}